// Round 17
// baseline (293.106 us; speedup 1.0000x reference)
//
#include <hip/hip_runtime.h>
#include <hip/hip_fp8.h>

#define NTOK 4096
#define HID 1024
#define QDIM 512
#define HEADS 4
#define NKEYS 128
#define TOPK 8
#define INTERDIM 4096

typedef __bf16 bf16x8 __attribute__((ext_vector_type(8)));
typedef __bf16 bf16x4 __attribute__((ext_vector_type(4)));
typedef float f32x4 __attribute__((ext_vector_type(4)));
typedef float f32x2 __attribute__((ext_vector_type(2)));

__device__ __forceinline__ float siluf(float x) { return x / (1.f + __expf(-x)); }
__device__ __forceinline__ unsigned sortable(float f) {
  unsigned u = __float_as_uint(f);
  return (u & 0x80000000u) ? ~u : (u | 0x80000000u);
}
__device__ __forceinline__ float bfl(unsigned u) { return __uint_as_float(u << 16); }
__device__ __forceinline__ float bfh(unsigned u) { return __uint_as_float(u & 0xFFFF0000u); }

// ---- fp8 e4m3 (OCP) encode/decode, HW path on gfx950 ----
__device__ __forceinline__ unsigned fp8x4_enc(float4 v) {
#if __has_builtin(__builtin_amdgcn_cvt_pk_fp8_f32)
  unsigned u = __builtin_amdgcn_cvt_pk_fp8_f32(v.x, v.y, 0, false);
  u = __builtin_amdgcn_cvt_pk_fp8_f32(v.z, v.w, u, true);
  return u;
#else
  __hip_fp8_e4m3 a(v.x), b(v.y), c(v.z), d(v.w);
  return (unsigned)a.__x | ((unsigned)b.__x << 8) | ((unsigned)c.__x << 16) | ((unsigned)d.__x << 24);
#endif
}
__device__ __forceinline__ void fp8x4_dec(unsigned u, float* o) {
#if __has_builtin(__builtin_amdgcn_cvt_pk_f32_fp8)
  f32x2 lo = __builtin_amdgcn_cvt_pk_f32_fp8(u, false);
  f32x2 hi = __builtin_amdgcn_cvt_pk_f32_fp8(u, true);
  o[0] = lo[0]; o[1] = lo[1]; o[2] = hi[0]; o[3] = hi[1];
#else
#pragma unroll
  for (int j = 0; j < 4; ++j) {
    const unsigned b = (u >> (8 * j)) & 0xFF;
    const unsigned e = (b >> 3) & 15, m = b & 7;
    float v = e ? __uint_as_float(((e + 120) << 23) | (m << 20)) : (float)m * 0x1p-9f;
    o[j] = (b & 0x80) ? -v : v;
  }
#endif
}

#define GLD_LDS16(g, l)                                                                   \
  __builtin_amdgcn_global_load_lds(                                                      \
      (const __attribute__((address_space(1))) unsigned int*)(g),                        \
      (__attribute__((address_space(3))) unsigned int*)(l), 16, 0, 0)

// ---------------- merged fp32 -> bf16 casts ----------------
__device__ __forceinline__ void cast_one_f4(const float* __restrict__ src,
                                            __bf16* __restrict__ dst, int i)
{
  const float4 v = ((const float4*)src)[i];
  bf16x4 o;
  o[0] = (__bf16)v.x; o[1] = (__bf16)v.y; o[2] = (__bf16)v.z; o[3] = (__bf16)v.w;
  ((bf16x4*)dst)[i] = o;
}

// hs 4096 | wq 512 | wg 4096 | wu 4096 | wd 4096  => 16896 blocks
__global__ __launch_bounds__(256) void cast5_kernel(
    const float* __restrict__ hs, const float* __restrict__ wq,
    const float* __restrict__ wg, const float* __restrict__ wu,
    const float* __restrict__ wd,
    __bf16* __restrict__ hs_o, __bf16* __restrict__ wq_o,
    __bf16* __restrict__ wg_o, __bf16* __restrict__ wu_o,
    __bf16* __restrict__ wd_o)
{
  int b = blockIdx.x;
  const float* src; __bf16* dst;
  if      (b < 4096)  { src = hs; dst = hs_o; }
  else if (b < 4608)  { src = wq; dst = wq_o; b -= 4096; }
  else if (b < 8704)  { src = wg; dst = wg_o; b -= 4608; }
  else if (b < 12800) { src = wu; dst = wu_o; b -= 8704; }
  else                { src = wd; dst = wd_o; b -= 12800; }
  cast_one_f4(src, dst, b * 256 + threadIdx.x);
}

// embeds -> fp8: dwe 16384 | upe 16384 blocks, 1 float4 -> 1 uint per thread
__global__ __launch_bounds__(256) void cast2_kernel(
    const float* __restrict__ dwe, const float* __restrict__ upe,
    unsigned* __restrict__ dwe_o, unsigned* __restrict__ upe_o)
{
  int b = blockIdx.x;
  const float* src; unsigned* dst;
  if (b < 16384) { src = dwe; dst = dwe_o; }
  else           { src = upe; dst = upe_o; b -= 16384; }
  const int i = b * 256 + threadIdx.x;
  dst[i] = fp8x4_enc(((const float4*)src)[i]);
}

// ---------------- WK precompute: WK[z][k][d] = sum_n keys[h,k,p,n] * Wq[p*256+h*64+n, d]
// z = p*4+h. One block per (z,k); 256 threads x 4 d's. Reads f32 keys/Wq directly.
__global__ __launch_bounds__(256) void wk_kernel(
    const float* __restrict__ keys,  // [h][k][p][64] f32
    const float* __restrict__ wq,    // [512][1024] f32
    __bf16* __restrict__ wk)         // [8*128][1024] bf16
{
  const int zk = blockIdx.x;      // z*128 + k
  const int z = zk >> 7, k = zk & 127;
  const int p = z >> 2, h = z & 3;
  __shared__ float kv[64];
  if (threadIdx.x < 64)
    kv[threadIdx.x] = keys[(((size_t)(h * NKEYS + k) * 2) + p) * 64 + threadIdx.x];
  __syncthreads();

  const int d0 = threadIdx.x * 4;
  const float* wrow = wq + (size_t)(p * 256 + h * 64) * HID + d0;
  float acc[4] = {};
#pragma unroll 8
  for (int n = 0; n < 64; ++n) {
    const float kn = kv[n];
    const float4 w = *(const float4*)(wrow + (size_t)n * HID);
    acc[0] += kn * w.x; acc[1] += kn * w.y; acc[2] += kn * w.z; acc[3] += kn * w.w;
  }
  bf16x4 o;
  o[0] = (__bf16)acc[0]; o[1] = (__bf16)acc[1]; o[2] = (__bf16)acc[2]; o[3] = (__bf16)acc[3];
  ((bf16x4*)(wk + (size_t)zk * HID))[threadIdx.x] = o;
}

// ---------------- bf16 MFMA GEMM (round-12 proven 2-barrier): C = A @ B^T ----------
// split-K via gridDim.z: z=0 writes f32 Cv, z>0 writes bf16 partial Cv1[(z-1)*M rows].
template<bool DUAL, bool OUT_BF16>
__global__ __launch_bounds__(512) void gemm_mfma(
    const __bf16* __restrict__ A, const __bf16* __restrict__ B0,
    const __bf16* __restrict__ B1, void* __restrict__ Cv, __bf16* __restrict__ Cv1,
    int M, int N, int K, int LD, int BW, int BH, int NRX)
{
  __shared__ __attribute__((aligned(16))) __bf16 As [128 * 32];
  __shared__ __attribute__((aligned(16))) __bf16 Bs0[128 * 32];
  __shared__ __attribute__((aligned(16))) __bf16 Bs1[DUAL ? 128 * 32 : 8];

  const int bid = blockIdx.y * gridDim.x + blockIdx.x;
  const int xcd = bid & 7, idx = bid >> 3;
  const int rx = (xcd % NRX) * BW;
  const int ry = (xcd / NRX) * BH;
  const int bx = rx + idx % BW;
  const int by = ry + idx / BW;

  const int kz = blockIdx.z * K;

  const int tid  = threadIdx.x;
  const int wave = tid >> 6;
  const int lane = tid & 63;
  const int m0 = by * 128;
  const int n0 = bx * 128;
  const int wr = wave >> 2, wc = wave & 3;
  const int lhi = lane >> 4, llo = lane & 15;

  f32x4 acc0[4][2] = {};
  f32x4 acc1[4][2] = {};

  const int r0 = tid >> 2, col0 = (tid & 3) * 8;
  const __bf16* Ag  = A  + kz + (size_t)(m0 + r0) * LD + col0;
  const __bf16* B0g = B0 + kz + (size_t)(n0 + r0) * LD + col0;
  const __bf16* B1g = DUAL ? (B1 + kz + (size_t)(n0 + r0) * LD + col0) : nullptr;
  __bf16* ldsA  = &As [(size_t)wave * 512];
  __bf16* ldsB0 = &Bs0[(size_t)wave * 512];
  __bf16* ldsB1 = &Bs1[(size_t)wave * 512];

  for (int k0 = 0; k0 < K; k0 += 32) {
    GLD_LDS16(Ag  + k0, ldsA);
    GLD_LDS16(B0g + k0, ldsB0);
    if constexpr (DUAL)
      GLD_LDS16(B1g + k0, ldsB1);
    __syncthreads();

    bf16x8 afr[4], bfr0[2], bfr1[2];
#pragma unroll
    for (int mi = 0; mi < 4; ++mi)
      afr[mi] = *(const bf16x8*)&As[(wr * 64 + mi * 16 + llo) * 32 + lhi * 8];
#pragma unroll
    for (int nj = 0; nj < 2; ++nj)
      bfr0[nj] = *(const bf16x8*)&Bs0[(wc * 32 + nj * 16 + llo) * 32 + lhi * 8];
    if constexpr (DUAL) {
#pragma unroll
      for (int nj = 0; nj < 2; ++nj)
        bfr1[nj] = *(const bf16x8*)&Bs1[(wc * 32 + nj * 16 + llo) * 32 + lhi * 8];
    }
#pragma unroll
    for (int mi = 0; mi < 4; ++mi)
#pragma unroll
      for (int nj = 0; nj < 2; ++nj) {
        acc0[mi][nj] = __builtin_amdgcn_mfma_f32_16x16x32_bf16(afr[mi], bfr0[nj], acc0[mi][nj], 0, 0, 0);
        if constexpr (DUAL)
          acc1[mi][nj] = __builtin_amdgcn_mfma_f32_16x16x32_bf16(afr[mi], bfr1[nj], acc1[mi][nj], 0, 0, 0);
      }
    __syncthreads();
  }

#pragma unroll
  for (int mi = 0; mi < 4; ++mi)
#pragma unroll
    for (int nj = 0; nj < 2; ++nj)
#pragma unroll
      for (int r = 0; r < 4; ++r) {
        const int row = m0 + wr * 64 + mi * 16 + lhi * 4 + r;
        const int col = n0 + wc * 32 + nj * 16 + llo;
        float v = acc0[mi][nj][r];
        if constexpr (DUAL) v = siluf(v) * acc1[mi][nj][r];
        if constexpr (OUT_BF16) {
          ((__bf16*)Cv)[(size_t)row * N + col] = (__bf16)v;
        } else {
          if (blockIdx.z == 0) ((float*)Cv)[(size_t)row * N + col] = v;
          else Cv1[((size_t)(blockIdx.z - 1) * M + row) * N + col] = (__bf16)v;
        }
      }
}

// ---------------- topk: 16 tokens x 1 head per block; S layout [tok][z*128+j] ---------
__global__ __launch_bounds__(256) void topk_kernel(
    const float* __restrict__ S,   // [4096][1024], col = (p*4+h)*128 + j
    int* __restrict__ out_idx,
    float* __restrict__ out_prob)
{
  const int g = blockIdx.x;
  const int h = blockIdx.y;
  const int t = threadIdx.x;
  const int tok0 = g * 16;

  __shared__ float    sims  [16][2][128];
  __shared__ unsigned packed[16][2][128];
  __shared__ unsigned cmax  [16][2][8];
  __shared__ int      cnt   [16][2];
  __shared__ unsigned char surv[16][2][128];
  __shared__ float    stv   [16][2][8];
  __shared__ unsigned char sti[16][2][8];
  __shared__ unsigned cnd   [16][64];

  const int ltok = t >> 4, j0 = (t & 15) * 8;
  unsigned pk[2][8];
#pragma unroll
  for (int p = 0; p < 2; ++p) {
    const float* src = S + (size_t)(tok0 + ltok) * 1024 + (p * 4 + h) * 128 + j0;
    const float4 a = ((const float4*)src)[0];
    const float4 b = ((const float4*)src)[1];
    float v[8] = {a.x, a.y, a.z, a.w, b.x, b.y, b.z, b.w};
#pragma unroll
    for (int e = 0; e < 8; ++e) {
      const unsigned u = (sortable(v[e]) & 0xFFFFFF80u) | (unsigned)(127 - (j0 + e));
      sims  [ltok][p][j0 + e] = v[e];
      packed[ltok][p][j0 + e] = u;
      pk[p][e] = u;
    }
  }
  if (t < 32) cnt[t >> 1][t & 1] = 0;
  __syncthreads();

  {
    const int ctok = t >> 4, cp = (t >> 3) & 1, c = t & 7;
    const uint4* q = (const uint4*)&packed[ctok][cp][c * 16];
    unsigned m = 0;
#pragma unroll
    for (int r = 0; r < 4; ++r) {
      const uint4 u = q[r];
      m = max(m, max(max(u.x, u.y), max(u.z, u.w)));
    }
    cmax[ctok][cp][c] = m;
  }
  __syncthreads();

#pragma unroll
  for (int p = 0; p < 2; ++p) {
    const uint4* cm = (const uint4*)&cmax[ltok][p][0];
    const uint4 ca = cm[0], cb = cm[1];
    const unsigned t0 = min(min(min(ca.x, ca.y), min(ca.z, ca.w)),
                            min(min(cb.x, cb.y), min(cb.z, cb.w)));
#pragma unroll
    for (int e = 0; e < 8; ++e) {
      if (pk[p][e] >= t0) {
        const int s = atomicAdd(&cnt[ltok][p], 1);
        surv[ltok][p][s] = (unsigned char)(j0 + e);
      }
    }
  }
  __syncthreads();

  {
    const int gid = t >> 3, lane8 = t & 7;
    const int stok = gid >> 1, sp = gid & 1;
    const int n = cnt[stok][sp];
    const uint4* row = (const uint4*)&packed[stok][sp][0];
    for (int s = lane8; s < n; s += 8) {
      const int j = surv[stok][sp][s];
      const unsigned mypk = packed[stok][sp][j];
      int rk = 0;
#pragma unroll 8
      for (int q4 = 0; q4 < 32; ++q4) {
        const uint4 u = row[q4];
        rk += (u.x > mypk) + (u.y > mypk) + (u.z > mypk) + (u.w > mypk);
      }
      if (rk < TOPK) {
        stv[stok][sp][rk] = sims[stok][sp][j];
        sti[stok][sp][rk] = (unsigned char)j;
      }
    }
  }
  __syncthreads();

  const int w = t >> 6, l = t & 63;
  for (int round = 0; round < 4; ++round) {
    const int tok = w * 4 + round;
    const int ci = l >> 3, cj = l & 7;
    const float cv = stv[tok][0][ci] + stv[tok][1][cj];
    const unsigned cpk = (sortable(cv) & 0xFFFFFFC0u) | (unsigned)(63 - l);
    cnd[tok][l] = cpk;
    __syncthreads();
    int rk = 0;
    const uint4* row = (const uint4*)&cnd[tok][0];
#pragma unroll
    for (int q4 = 0; q4 < 16; ++q4) {
      const uint4 u = row[q4];
      rk += (u.x > cpk) + (u.y > cpk) + (u.z > cpk) + (u.w > cpk);
    }
    float mx = cv;
#pragma unroll
    for (int off = 32; off; off >>= 1) mx = fmaxf(mx, __shfl_xor(mx, off));
    const float e = (rk < TOPK) ? __expf(cv - mx) : 0.f;
    float sum = e;
#pragma unroll
    for (int off = 32; off; off >>= 1) sum += __shfl_xor(sum, off);
    if (rk < TOPK) {
      const int o = ((tok0 + tok) * HEADS + h) * TOPK + rk;
      out_idx [o] = (int)sti[tok][0][ci] * NKEYS + (int)sti[tok][1][cj];
      out_prob[o] = e / sum;
    }
  }
}

// ---------------- expert mixture: fp8 embeds, 4 waves x 8 experts, 2-expert pipelined --
__device__ __forceinline__ float dotf8(const float4* h, uint4 d)
{
  float o[16];
  fp8x4_dec(d.x, o);  fp8x4_dec(d.y, o + 4);
  fp8x4_dec(d.z, o + 8); fp8x4_dec(d.w, o + 12);
  float s = 0.f;
#pragma unroll
  for (int q = 0; q < 4; ++q)
    s += h[q].x * o[4*q] + h[q].y * o[4*q+1] + h[q].z * o[4*q+2] + h[q].w * o[4*q+3];
  return s;
}

template<int NPART>
__global__ __launch_bounds__(256) void expert_kernel(
    const float* __restrict__ hs,
    const unsigned char* __restrict__ down_e,  // [16384][1024] fp8
    const unsigned char* __restrict__ up_e,
    const int* __restrict__ idx,
    const float* __restrict__ prob,
    const __bf16* __restrict__ parts,
    float* __restrict__ out)
{
  const int token = blockIdx.x;
  const int t = threadIdx.x, w = t >> 6, l = t & 63;
  __shared__ float4 sred[4][256];

  const float4* hrow = (const float4*)(hs + (size_t)token * HID);
  float4 h[4];
#pragma unroll
  for (int q = 0; q < 4; ++q) h[q] = hrow[4 * l + q];
  float acc[16] = {};

  const int*   tidx  = idx  + token * 32 + w * 8;
  const float* tprob = prob + token * 32 + w * 8;

#pragma unroll
  for (int e = 0; e < 8; e += 2) {
    const int   ex0 = tidx[e],  ex1 = tidx[e + 1];
    const float pr0 = tprob[e], pr1 = tprob[e + 1];
    const uint4 d0 = ((const uint4*)(down_e + (size_t)ex0 * HID))[l];
    const uint4 d1 = ((const uint4*)(down_e + (size_t)ex1 * HID))[l];
    const uint4 u0 = ((const uint4*)(up_e   + (size_t)ex0 * HID))[l];
    const uint4 u1 = ((const uint4*)(up_e   + (size_t)ex1 * HID))[l];

    float part0 = dotf8(h, d0);
    float part1 = dotf8(h, d1);
#pragma unroll
    for (int off = 32; off; off >>= 1) {
      part0 += __shfl_xor(part0, off);
      part1 += __shfl_xor(part1, off);
    }
    const float w0 = siluf(part0) * pr0;
    const float w1 = siluf(part1) * pr1;

    float o0[16], o1[16];
    fp8x4_dec(u0.x, o0); fp8x4_dec(u0.y, o0 + 4); fp8x4_dec(u0.z, o0 + 8); fp8x4_dec(u0.w, o0 + 12);
    fp8x4_dec(u1.x, o1); fp8x4_dec(u1.y, o1 + 4); fp8x4_dec(u1.z, o1 + 8); fp8x4_dec(u1.w, o1 + 12);
#pragma unroll
    for (int j = 0; j < 16; ++j) acc[j] += w0 * o0[j] + w1 * o1[j];
  }
#pragma unroll
  for (int q = 0; q < 4; ++q)
    sred[w][4 * l + q] = make_float4(acc[4*q], acc[4*q+1], acc[4*q+2], acc[4*q+3]);
  __syncthreads();

  const float4 r0 = sred[0][t], r1 = sred[1][t], r2 = sred[2][t], r3 = sred[3][t];
  float4* o = (float4*)(out + (size_t)token * HID);
  float4 cur = o[t];
  if constexpr (NPART > 0) {
#pragma unroll
    for (int q = 0; q < NPART; ++q) {
      const uint2 pb = ((const uint2*)(parts + ((size_t)q * NTOK + token) * HID))[t];
      cur.x += bfl(pb.x); cur.y += bfh(pb.x);
      cur.z += bfl(pb.y); cur.w += bfh(pb.y);
    }
  }
  cur.x += r0.x + r1.x + r2.x + r3.x;
  cur.y += r0.y + r1.y + r2.y + r3.y;
  cur.z += r0.z + r1.z + r2.z + r3.z;
  cur.w += r0.w + r1.w + r2.w + r3.w;
  o[t] = cur;
}

extern "C" void kernel_launch(void* const* d_in, const int* in_sizes, int n_in,
                              void* d_out, int out_size, void* d_ws, size_t ws_size,
                              hipStream_t stream)
{
  const float* hs   = (const float*)d_in[0];
  const float* Wq   = (const float*)d_in[1];
  const float* keys = (const float*)d_in[2];
  const float* dwe  = (const float*)d_in[3];
  const float* upe  = (const float*)d_in[4];
  const float* Wg   = (const float*)d_in[5];
  const float* Wu   = (const float*)d_in[6];
  const float* Wd   = (const float*)d_in[7];
  float* out = (float*)d_out;

  __bf16* wkbf    = (__bf16*)d_ws;                        // 8*128*1024 bf16 (2MB)
  int*    idxb    = (int*)(wkbf + (size_t)8 * NKEYS * HID);
  float*  probb   = (float*)(idxb + NTOK * HEADS * TOPK);
  __bf16* hs_bf   = (__bf16*)(probb + NTOK * HEADS * TOPK);
  __bf16* wq_bf   = hs_bf + (size_t)NTOK * HID;
  __bf16* wg_bf   = wq_bf + (size_t)QDIM * HID;
  __bf16* wu_bf   = wg_bf + (size_t)INTERDIM * HID;
  __bf16* wd_bf   = wu_bf + (size_t)INTERDIM * HID;
  __bf16* interbf = wd_bf + (size_t)HID * INTERDIM;       // 32MB
  __bf16* parts   = interbf + (size_t)NTOK * INTERDIM;    // up to 3 x 8MB partials
  float*  simsb   = (float*)interbf;                      // overlay (16MB), dead before dual-gemm
  unsigned char* dwe_f8 = (unsigned char*)interbf;        // 16MB overlay, after down-GEMM
  unsigned char* upe_f8 = (unsigned char*)hs_bf;          // 16MB overlay (hs..wd span 33MB)

  const size_t base  = (size_t)((char*)parts - (char*)d_ws);
  const size_t psz   = (size_t)NTOK * HID * sizeof(__bf16);  // 8MB per partial
  int nsplit = 1;
  if      (ws_size >= base + 3 * psz) nsplit = 4;
  else if (ws_size >= base + 1 * psz) nsplit = 2;

  // casts (2 launches)
  cast5_kernel<<<16896, 256, 0, stream>>>(hs, Wq, Wg, Wu, Wd,
                                          hs_bf, wq_bf, wg_bf, wu_bf, wd_bf);
  // WK = keys @ Wq_slice (f32 in, bf16 out) — folds q-proj into retrieval
  wk_kernel<<<8 * NKEYS, 256, 0, stream>>>(keys, Wq, wkbf);

  // sims = hs @ WK^T  (f32 out, one GEMM: M=4096, N=1024, K=1024). regions 8x4, NRX=1
  gemm_mfma<false, false><<<dim3(8, NTOK / 128), 512, 0, stream>>>(
      hs_bf, wkbf, nullptr, simsb, nullptr, NTOK, 1024, HID, HID, 8, 4, 1);

  // topk (S layout [tok][z*128+j])
  topk_kernel<<<dim3(NTOK / 16, HEADS), 256, 0, stream>>>(simsb, idxb, probb);

  // inter = silu(hs @ Wg^T) * (hs @ Wu^T)  (bf16 out). regions 8x16, NRX=4
  gemm_mfma<true, true><<<dim3(INTERDIM / 128, NTOK / 128), 512, 0, stream>>>(
      hs_bf, wg_bf, wu_bf, interbf, nullptr, NTOK, INTERDIM, HID, HID, 8, 16, 4);

  // out = inter @ Wd^T  (f32 out). regions 8x4, NRX=1. split-K = nsplit.
  gemm_mfma<false, false><<<dim3(HID / 128, NTOK / 128, nsplit), 512, 0, stream>>>(
      interbf, wd_bf, nullptr, out, parts, NTOK, HID, INTERDIM / nsplit, INTERDIM, 8, 4, 1);

  // expert embeds -> fp8 (one launch), then expert mixture (+ partials)
  cast2_kernel<<<32768, 256, 0, stream>>>(dwe, upe, (unsigned*)dwe_f8, (unsigned*)upe_f8);
  if (nsplit == 4)
    expert_kernel<3><<<NTOK, 256, 0, stream>>>(hs, dwe_f8, upe_f8, idxb, probb, parts, out);
  else if (nsplit == 2)
    expert_kernel<1><<<NTOK, 256, 0, stream>>>(hs, dwe_f8, upe_f8, idxb, probb, parts, out);
  else
    expert_kernel<0><<<NTOK, 256, 0, stream>>>(hs, dwe_f8, upe_f8, idxb, probb, nullptr, out);
}

// Round 18
// 279.360 us; speedup vs baseline: 1.0492x; 1.0492x over previous
//
#include <hip/hip_runtime.h>
#include <hip/hip_fp8.h>

#define NTOK 4096
#define HID 1024
#define QDIM 512
#define HEADS 4
#define NKEYS 128
#define TOPK 8
#define INTERDIM 4096

typedef __bf16 bf16x8 __attribute__((ext_vector_type(8)));
typedef __bf16 bf16x4 __attribute__((ext_vector_type(4)));
typedef float f32x4 __attribute__((ext_vector_type(4)));
typedef float f32x2 __attribute__((ext_vector_type(2)));

__device__ __forceinline__ float siluf(float x) { return x / (1.f + __expf(-x)); }
__device__ __forceinline__ unsigned sortable(float f) {
  unsigned u = __float_as_uint(f);
  return (u & 0x80000000u) ? ~u : (u | 0x80000000u);
}
__device__ __forceinline__ float bfl(unsigned u) { return __uint_as_float(u << 16); }
__device__ __forceinline__ float bfh(unsigned u) { return __uint_as_float(u & 0xFFFF0000u); }

// ---- fp8 e4m3 (OCP) encode/decode, HW path on gfx950 ----
__device__ __forceinline__ unsigned fp8x4_enc(float4 v) {
#if __has_builtin(__builtin_amdgcn_cvt_pk_fp8_f32)
  unsigned u = __builtin_amdgcn_cvt_pk_fp8_f32(v.x, v.y, 0, false);
  u = __builtin_amdgcn_cvt_pk_fp8_f32(v.z, v.w, u, true);
  return u;
#else
  __hip_fp8_e4m3 a(v.x), b(v.y), c(v.z), d(v.w);
  return (unsigned)a.__x | ((unsigned)b.__x << 8) | ((unsigned)c.__x << 16) | ((unsigned)d.__x << 24);
#endif
}
__device__ __forceinline__ void fp8x4_dec(unsigned u, float* o) {
#if __has_builtin(__builtin_amdgcn_cvt_pk_f32_fp8)
  f32x2 lo = __builtin_amdgcn_cvt_pk_f32_fp8(u, false);
  f32x2 hi = __builtin_amdgcn_cvt_pk_f32_fp8(u, true);
  o[0] = lo[0]; o[1] = lo[1]; o[2] = hi[0]; o[3] = hi[1];
#else
#pragma unroll
  for (int j = 0; j < 4; ++j) {
    const unsigned b = (u >> (8 * j)) & 0xFF;
    const unsigned e = (b >> 3) & 15, m = b & 7;
    float v = e ? __uint_as_float(((e + 120) << 23) | (m << 20)) : (float)m * 0x1p-9f;
    o[j] = (b & 0x80) ? -v : v;
  }
#endif
}

#define GLD_LDS16(g, l)                                                                   \
  __builtin_amdgcn_global_load_lds(                                                      \
      (const __attribute__((address_space(1))) unsigned int*)(g),                        \
      (__attribute__((address_space(3))) unsigned int*)(l), 16, 0, 0)

// ---------------- merged fp32 -> bf16 casts (weights + keys in ONE launch) ----------------
__device__ __forceinline__ void cast_one_f4(const float* __restrict__ src,
                                            __bf16* __restrict__ dst, int i)
{
  const float4 v = ((const float4*)src)[i];
  bf16x4 o;
  o[0] = (__bf16)v.x; o[1] = (__bf16)v.y; o[2] = (__bf16)v.z; o[3] = (__bf16)v.w;
  ((bf16x4*)dst)[i] = o;
}

// hs 4096 | wq 512 | wg 4096 | wu 4096 | wd 4096 | keys 256  => 17152 blocks
__global__ __launch_bounds__(256) void cast6_kernel(
    const float* __restrict__ hs, const float* __restrict__ wq,
    const float* __restrict__ wg, const float* __restrict__ wu,
    const float* __restrict__ wd, const float* __restrict__ keys,
    __bf16* __restrict__ hs_o, __bf16* __restrict__ wq_o,
    __bf16* __restrict__ wg_o, __bf16* __restrict__ wu_o,
    __bf16* __restrict__ wd_o, __bf16* __restrict__ kbf)
{
  int b = blockIdx.x;
  if (b >= 16896) {  // keys: layout transform, scalar
    const int i = (b - 16896) * 256 + threadIdx.x;  // 4*128*2*64 = 65536
    const int n = i & 63, p = (i >> 6) & 1, k = (i >> 7) & 127, h = (i >> 14) & 3;
    kbf[(((size_t)(p * 4 + h) * NKEYS) + k) * 64 + n] = (__bf16)keys[i];
    return;
  }
  const float* src; __bf16* dst;
  if      (b < 4096)  { src = hs; dst = hs_o; }
  else if (b < 4608)  { src = wq; dst = wq_o; b -= 4096; }
  else if (b < 8704)  { src = wg; dst = wg_o; b -= 4608; }
  else if (b < 12800) { src = wu; dst = wu_o; b -= 8704; }
  else                { src = wd; dst = wd_o; b -= 12800; }
  cast_one_f4(src, dst, b * 256 + threadIdx.x);
}

// embeds -> fp8: dwe 16384 | upe 16384 blocks, 1 float4 -> 1 uint per thread
__global__ __launch_bounds__(256) void cast2_kernel(
    const float* __restrict__ dwe, const float* __restrict__ upe,
    unsigned* __restrict__ dwe_o, unsigned* __restrict__ upe_o)
{
  int b = blockIdx.x;
  const float* src; unsigned* dst;
  if (b < 16384) { src = dwe; dst = dwe_o; }
  else           { src = upe; dst = upe_o; b -= 16384; }
  const int i = b * 256 + threadIdx.x;
  dst[i] = fp8x4_enc(((const float4*)src)[i]);
}

// ---------------- bf16 MFMA GEMM (round-12 proven 2-barrier): C = A @ B^T ----------
// split-K via gridDim.z: z=0 writes f32 Cv, z>0 writes bf16 partial Cv1[(z-1)*M rows].
template<bool DUAL, bool OUT_BF16>
__global__ __launch_bounds__(512) void gemm_mfma(
    const __bf16* __restrict__ A, const __bf16* __restrict__ B0,
    const __bf16* __restrict__ B1, void* __restrict__ Cv, __bf16* __restrict__ Cv1,
    int M, int N, int K, int LD, int BW, int BH, int NRX)
{
  __shared__ __attribute__((aligned(16))) __bf16 As [128 * 32];
  __shared__ __attribute__((aligned(16))) __bf16 Bs0[128 * 32];
  __shared__ __attribute__((aligned(16))) __bf16 Bs1[DUAL ? 128 * 32 : 8];

  const int bid = blockIdx.y * gridDim.x + blockIdx.x;
  const int xcd = bid & 7, idx = bid >> 3;
  const int rx = (xcd % NRX) * BW;
  const int ry = (xcd / NRX) * BH;
  const int bx = rx + idx % BW;
  const int by = ry + idx / BW;

  const int kz = blockIdx.z * K;

  const int tid  = threadIdx.x;
  const int wave = tid >> 6;
  const int lane = tid & 63;
  const int m0 = by * 128;
  const int n0 = bx * 128;
  const int wr = wave >> 2, wc = wave & 3;
  const int lhi = lane >> 4, llo = lane & 15;

  f32x4 acc0[4][2] = {};
  f32x4 acc1[4][2] = {};

  const int r0 = tid >> 2, col0 = (tid & 3) * 8;
  const __bf16* Ag  = A  + kz + (size_t)(m0 + r0) * LD + col0;
  const __bf16* B0g = B0 + kz + (size_t)(n0 + r0) * LD + col0;
  const __bf16* B1g = DUAL ? (B1 + kz + (size_t)(n0 + r0) * LD + col0) : nullptr;
  __bf16* ldsA  = &As [(size_t)wave * 512];
  __bf16* ldsB0 = &Bs0[(size_t)wave * 512];
  __bf16* ldsB1 = &Bs1[(size_t)wave * 512];

  for (int k0 = 0; k0 < K; k0 += 32) {
    GLD_LDS16(Ag  + k0, ldsA);
    GLD_LDS16(B0g + k0, ldsB0);
    if constexpr (DUAL)
      GLD_LDS16(B1g + k0, ldsB1);
    __syncthreads();

    bf16x8 afr[4], bfr0[2], bfr1[2];
#pragma unroll
    for (int mi = 0; mi < 4; ++mi)
      afr[mi] = *(const bf16x8*)&As[(wr * 64 + mi * 16 + llo) * 32 + lhi * 8];
#pragma unroll
    for (int nj = 0; nj < 2; ++nj)
      bfr0[nj] = *(const bf16x8*)&Bs0[(wc * 32 + nj * 16 + llo) * 32 + lhi * 8];
    if constexpr (DUAL) {
#pragma unroll
      for (int nj = 0; nj < 2; ++nj)
        bfr1[nj] = *(const bf16x8*)&Bs1[(wc * 32 + nj * 16 + llo) * 32 + lhi * 8];
    }
#pragma unroll
    for (int mi = 0; mi < 4; ++mi)
#pragma unroll
      for (int nj = 0; nj < 2; ++nj) {
        acc0[mi][nj] = __builtin_amdgcn_mfma_f32_16x16x32_bf16(afr[mi], bfr0[nj], acc0[mi][nj], 0, 0, 0);
        if constexpr (DUAL)
          acc1[mi][nj] = __builtin_amdgcn_mfma_f32_16x16x32_bf16(afr[mi], bfr1[nj], acc1[mi][nj], 0, 0, 0);
      }
    __syncthreads();
  }

#pragma unroll
  for (int mi = 0; mi < 4; ++mi)
#pragma unroll
    for (int nj = 0; nj < 2; ++nj)
#pragma unroll
      for (int r = 0; r < 4; ++r) {
        const int row = m0 + wr * 64 + mi * 16 + lhi * 4 + r;
        const int col = n0 + wc * 32 + nj * 16 + llo;
        float v = acc0[mi][nj][r];
        if constexpr (DUAL) v = siluf(v) * acc1[mi][nj][r];
        if constexpr (OUT_BF16) {
          ((__bf16*)Cv)[(size_t)row * N + col] = (__bf16)v;
        } else {
          if (blockIdx.z == 0) ((float*)Cv)[(size_t)row * N + col] = v;
          else Cv1[((size_t)(blockIdx.z - 1) * M + row) * N + col] = (__bf16)v;
        }
      }
}

// ---------------- batched sims GEMM (round-9) ----------------
__global__ __launch_bounds__(256) void sims_gemm(
    const __bf16* __restrict__ Qbf,  // [4096][512]
    const __bf16* __restrict__ Kbf,  // [8][128][64]
    float* __restrict__ S)           // [8][4096][128]
{
  __shared__ __attribute__((aligned(16))) __bf16 As[128 * 32];
  __shared__ __attribute__((aligned(16))) __bf16 Bs[128 * 32];

  const int z = blockIdx.y;
  const int p = z >> 2, h = z & 3;
  const __bf16* A = Qbf + p * 256 + h * 64;
  const __bf16* B = Kbf + (size_t)z * NKEYS * 64;
  float* C = S + (size_t)z * NTOK * NKEYS;

  const int tid  = threadIdx.x;
  const int wave = tid >> 6;
  const int lane = tid & 63;
  const int m0 = blockIdx.x * 128;
  const int wr = wave >> 1, wc = wave & 1;
  const int lhi = lane >> 4, llo = lane & 15;

  f32x4 acc[4][4] = {};

  const int c0 = tid, c1 = 256 + tid;
  const int r0 = c0 >> 2, col0 = (c0 & 3) * 8;
  const int r1 = c1 >> 2, col1 = (c1 & 3) * 8;
  __bf16* ldsA0 = &As[(wave * 64) * 8];
  __bf16* ldsA1 = &As[(256 + wave * 64) * 8];
  __bf16* ldsB0 = &Bs[(wave * 64) * 8];
  __bf16* ldsB1 = &Bs[(256 + wave * 64) * 8];

  for (int k0 = 0; k0 < 64; k0 += 32) {
    GLD_LDS16(A + (size_t)(m0 + r0) * 512 + k0 + col0, ldsA0);
    GLD_LDS16(A + (size_t)(m0 + r1) * 512 + k0 + col1, ldsA1);
    GLD_LDS16(B + (size_t)r0 * 64 + k0 + col0, ldsB0);
    GLD_LDS16(B + (size_t)r1 * 64 + k0 + col1, ldsB1);
    __syncthreads();

    bf16x8 afr[4], bfr[4];
#pragma unroll
    for (int mi = 0; mi < 4; ++mi)
      afr[mi] = *(const bf16x8*)&As[(wr * 64 + mi * 16 + llo) * 32 + lhi * 8];
#pragma unroll
    for (int nj = 0; nj < 4; ++nj)
      bfr[nj] = *(const bf16x8*)&Bs[(wc * 64 + nj * 16 + llo) * 32 + lhi * 8];
#pragma unroll
    for (int mi = 0; mi < 4; ++mi)
#pragma unroll
      for (int nj = 0; nj < 4; ++nj)
        acc[mi][nj] = __builtin_amdgcn_mfma_f32_16x16x32_bf16(afr[mi], bfr[nj], acc[mi][nj], 0, 0, 0);
    __syncthreads();
  }

#pragma unroll
  for (int mi = 0; mi < 4; ++mi)
#pragma unroll
    for (int nj = 0; nj < 4; ++nj)
#pragma unroll
      for (int r = 0; r < 4; ++r) {
        const int row = m0 + wr * 64 + mi * 16 + lhi * 4 + r;
        const int col = wc * 64 + nj * 16 + llo;
        C[(size_t)row * NKEYS + col] = acc[mi][nj][r];
      }
}

// ---------------- topk (round-9 proven): 16 tokens x 1 head per block ----------------
__global__ __launch_bounds__(256) void topk_kernel(
    const float* __restrict__ S,   // [8][4096][128]  (z = p*4+h)
    int* __restrict__ out_idx,
    float* __restrict__ out_prob)
{
  const int g = blockIdx.x;
  const int h = blockIdx.y;
  const int t = threadIdx.x;
  const int tok0 = g * 16;

  __shared__ float    sims  [16][2][128];
  __shared__ unsigned packed[16][2][128];
  __shared__ unsigned cmax  [16][2][8];
  __shared__ int      cnt   [16][2];
  __shared__ unsigned char surv[16][2][128];
  __shared__ float    stv   [16][2][8];
  __shared__ unsigned char sti[16][2][8];
  __shared__ unsigned cnd   [16][64];

  const int ltok = t >> 4, j0 = (t & 15) * 8;
  unsigned pk[2][8];
#pragma unroll
  for (int p = 0; p < 2; ++p) {
    const float* src = S + (((size_t)(p * 4 + h) * NTOK) + tok0 + ltok) * NKEYS + j0;
    const float4 a = ((const float4*)src)[0];
    const float4 b = ((const float4*)src)[1];
    float v[8] = {a.x, a.y, a.z, a.w, b.x, b.y, b.z, b.w};
#pragma unroll
    for (int e = 0; e < 8; ++e) {
      const unsigned u = (sortable(v[e]) & 0xFFFFFF80u) | (unsigned)(127 - (j0 + e));
      sims  [ltok][p][j0 + e] = v[e];
      packed[ltok][p][j0 + e] = u;
      pk[p][e] = u;
    }
  }
  if (t < 32) cnt[t >> 1][t & 1] = 0;
  __syncthreads();

  {
    const int ctok = t >> 4, cp = (t >> 3) & 1, c = t & 7;
    const uint4* q = (const uint4*)&packed[ctok][cp][c * 16];
    unsigned m = 0;
#pragma unroll
    for (int r = 0; r < 4; ++r) {
      const uint4 u = q[r];
      m = max(m, max(max(u.x, u.y), max(u.z, u.w)));
    }
    cmax[ctok][cp][c] = m;
  }
  __syncthreads();

#pragma unroll
  for (int p = 0; p < 2; ++p) {
    const uint4* cm = (const uint4*)&cmax[ltok][p][0];
    const uint4 ca = cm[0], cb = cm[1];
    const unsigned t0 = min(min(min(ca.x, ca.y), min(ca.z, ca.w)),
                            min(min(cb.x, cb.y), min(cb.z, cb.w)));
#pragma unroll
    for (int e = 0; e < 8; ++e) {
      if (pk[p][e] >= t0) {
        const int s = atomicAdd(&cnt[ltok][p], 1);
        surv[ltok][p][s] = (unsigned char)(j0 + e);
      }
    }
  }
  __syncthreads();

  {
    const int gid = t >> 3, lane8 = t & 7;
    const int stok = gid >> 1, sp = gid & 1;
    const int n = cnt[stok][sp];
    const uint4* row = (const uint4*)&packed[stok][sp][0];
    for (int s = lane8; s < n; s += 8) {
      const int j = surv[stok][sp][s];
      const unsigned mypk = packed[stok][sp][j];
      int rk = 0;
#pragma unroll 8
      for (int q4 = 0; q4 < 32; ++q4) {
        const uint4 u = row[q4];
        rk += (u.x > mypk) + (u.y > mypk) + (u.z > mypk) + (u.w > mypk);
      }
      if (rk < TOPK) {
        stv[stok][sp][rk] = sims[stok][sp][j];
        sti[stok][sp][rk] = (unsigned char)j;
      }
    }
  }
  __syncthreads();

  const int w = t >> 6, l = t & 63;
  for (int round = 0; round < 4; ++round) {
    const int tok = w * 4 + round;
    const int ci = l >> 3, cj = l & 7;
    const float cv = stv[tok][0][ci] + stv[tok][1][cj];
    const unsigned cpk = (sortable(cv) & 0xFFFFFFC0u) | (unsigned)(63 - l);
    cnd[tok][l] = cpk;
    __syncthreads();
    int rk = 0;
    const uint4* row = (const uint4*)&cnd[tok][0];
#pragma unroll
    for (int q4 = 0; q4 < 16; ++q4) {
      const uint4 u = row[q4];
      rk += (u.x > cpk) + (u.y > cpk) + (u.z > cpk) + (u.w > cpk);
    }
    float mx = cv;
#pragma unroll
    for (int off = 32; off; off >>= 1) mx = fmaxf(mx, __shfl_xor(mx, off));
    const float e = (rk < TOPK) ? __expf(cv - mx) : 0.f;
    float sum = e;
#pragma unroll
    for (int off = 32; off; off >>= 1) sum += __shfl_xor(sum, off);
    if (rk < TOPK) {
      const int o = ((tok0 + tok) * HEADS + h) * TOPK + rk;
      out_idx [o] = (int)sti[tok][0][ci] * NKEYS + (int)sti[tok][1][cj];
      out_prob[o] = e / sum;
    }
  }
}

// ---------------- expert mixture: fp8 embeds, 4 waves x 8 experts, 2-expert pipelined --
__device__ __forceinline__ float dotf8(const float4* h, uint4 d)
{
  float o[16];
  fp8x4_dec(d.x, o);  fp8x4_dec(d.y, o + 4);
  fp8x4_dec(d.z, o + 8); fp8x4_dec(d.w, o + 12);
  float s = 0.f;
#pragma unroll
  for (int q = 0; q < 4; ++q)
    s += h[q].x * o[4*q] + h[q].y * o[4*q+1] + h[q].z * o[4*q+2] + h[q].w * o[4*q+3];
  return s;
}

template<int NPART>
__global__ __launch_bounds__(256) void expert_kernel(
    const float* __restrict__ hs,
    const unsigned char* __restrict__ down_e,  // [16384][1024] fp8
    const unsigned char* __restrict__ up_e,
    const int* __restrict__ idx,
    const float* __restrict__ prob,
    const __bf16* __restrict__ parts,
    float* __restrict__ out)
{
  const int token = blockIdx.x;
  const int t = threadIdx.x, w = t >> 6, l = t & 63;
  __shared__ float4 sred[4][256];

  const float4* hrow = (const float4*)(hs + (size_t)token * HID);
  float4 h[4];
#pragma unroll
  for (int q = 0; q < 4; ++q) h[q] = hrow[4 * l + q];
  float acc[16] = {};

  const int*   tidx  = idx  + token * 32 + w * 8;
  const float* tprob = prob + token * 32 + w * 8;

#pragma unroll
  for (int e = 0; e < 8; e += 2) {
    const int   ex0 = tidx[e],  ex1 = tidx[e + 1];
    const float pr0 = tprob[e], pr1 = tprob[e + 1];
    const uint4 d0 = ((const uint4*)(down_e + (size_t)ex0 * HID))[l];
    const uint4 d1 = ((const uint4*)(down_e + (size_t)ex1 * HID))[l];
    const uint4 u0 = ((const uint4*)(up_e   + (size_t)ex0 * HID))[l];
    const uint4 u1 = ((const uint4*)(up_e   + (size_t)ex1 * HID))[l];

    float part0 = dotf8(h, d0);
    float part1 = dotf8(h, d1);
#pragma unroll
    for (int off = 32; off; off >>= 1) {
      part0 += __shfl_xor(part0, off);
      part1 += __shfl_xor(part1, off);
    }
    const float w0 = siluf(part0) * pr0;
    const float w1 = siluf(part1) * pr1;

    float o0[16], o1[16];
    fp8x4_dec(u0.x, o0); fp8x4_dec(u0.y, o0 + 4); fp8x4_dec(u0.z, o0 + 8); fp8x4_dec(u0.w, o0 + 12);
    fp8x4_dec(u1.x, o1); fp8x4_dec(u1.y, o1 + 4); fp8x4_dec(u1.z, o1 + 8); fp8x4_dec(u1.w, o1 + 12);
#pragma unroll
    for (int j = 0; j < 16; ++j) acc[j] += w0 * o0[j] + w1 * o1[j];
  }
#pragma unroll
  for (int q = 0; q < 4; ++q)
    sred[w][4 * l + q] = make_float4(acc[4*q], acc[4*q+1], acc[4*q+2], acc[4*q+3]);
  __syncthreads();

  const float4 r0 = sred[0][t], r1 = sred[1][t], r2 = sred[2][t], r3 = sred[3][t];
  float4* o = (float4*)(out + (size_t)token * HID);
  float4 cur = o[t];
  if constexpr (NPART > 0) {
#pragma unroll
    for (int q = 0; q < NPART; ++q) {
      const uint2 pb = ((const uint2*)(parts + ((size_t)q * NTOK + token) * HID))[t];
      cur.x += bfl(pb.x); cur.y += bfh(pb.x);
      cur.z += bfl(pb.y); cur.w += bfh(pb.y);
    }
  }
  cur.x += r0.x + r1.x + r2.x + r3.x;
  cur.y += r0.y + r1.y + r2.y + r3.y;
  cur.z += r0.z + r1.z + r2.z + r3.z;
  cur.w += r0.w + r1.w + r2.w + r3.w;
  o[t] = cur;
}

extern "C" void kernel_launch(void* const* d_in, const int* in_sizes, int n_in,
                              void* d_out, int out_size, void* d_ws, size_t ws_size,
                              hipStream_t stream)
{
  const float* hs   = (const float*)d_in[0];
  const float* Wq   = (const float*)d_in[1];
  const float* keys = (const float*)d_in[2];
  const float* dwe  = (const float*)d_in[3];
  const float* upe  = (const float*)d_in[4];
  const float* Wg   = (const float*)d_in[5];
  const float* Wu   = (const float*)d_in[6];
  const float* Wd   = (const float*)d_in[7];
  float* out = (float*)d_out;

  __bf16* qbf     = (__bf16*)d_ws;                        // 4MB
  __bf16* kbf     = qbf + (size_t)NTOK * QDIM;            // 128KB
  int*    idxb    = (int*)(kbf + 8 * NKEYS * 64);
  float*  probb   = (float*)(idxb + NTOK * HEADS * TOPK);
  __bf16* hs_bf   = (__bf16*)(probb + NTOK * HEADS * TOPK);
  __bf16* wq_bf   = hs_bf + (size_t)NTOK * HID;
  __bf16* wg_bf   = wq_bf + (size_t)QDIM * HID;
  __bf16* wu_bf   = wg_bf + (size_t)INTERDIM * HID;
  __bf16* wd_bf   = wu_bf + (size_t)INTERDIM * HID;
  __bf16* interbf = wd_bf + (size_t)HID * INTERDIM;       // 32MB
  __bf16* parts   = interbf + (size_t)NTOK * INTERDIM;    // up to 3 x 8MB partials
  float*  simsb   = (float*)interbf;                      // overlay (16MB), dead before dual-gemm
  unsigned char* dwe_f8 = (unsigned char*)interbf;        // 16MB overlay, after down-GEMM
  unsigned char* upe_f8 = (unsigned char*)hs_bf;          // 16MB overlay (hs..wd span 33MB)

  const size_t base  = (size_t)((char*)parts - (char*)d_ws);
  const size_t psz   = (size_t)NTOK * HID * sizeof(__bf16);  // 8MB per partial
  int nsplit = 1;
  if      (ws_size >= base + 3 * psz) nsplit = 4;
  else if (ws_size >= base + 1 * psz) nsplit = 2;

  // casts: weights + keys in ONE launch
  cast6_kernel<<<17152, 256, 0, stream>>>(hs, Wq, Wg, Wu, Wd, keys,
                                          hs_bf, wq_bf, wg_bf, wu_bf, wd_bf, kbf);

  // q = hs @ Wq^T  (bf16 out). regions 4x4, NRX=1
  gemm_mfma<false, true><<<dim3(QDIM / 128, NTOK / 128), 512, 0, stream>>>(
      hs_bf, wq_bf, nullptr, qbf, nullptr, NTOK, QDIM, HID, HID, 4, 4, 1);

  // sims + topk (round-9 split)
  sims_gemm<<<dim3(NTOK / 128, 8), 256, 0, stream>>>(qbf, kbf, simsb);
  topk_kernel<<<dim3(NTOK / 16, HEADS), 256, 0, stream>>>(simsb, idxb, probb);

  // inter = silu(hs @ Wg^T) * (hs @ Wu^T)  (bf16 out). regions 8x16, NRX=4
  gemm_mfma<true, true><<<dim3(INTERDIM / 128, NTOK / 128), 512, 0, stream>>>(
      hs_bf, wg_bf, wu_bf, interbf, nullptr, NTOK, INTERDIM, HID, HID, 8, 16, 4);

  // out = inter @ Wd^T  (f32 out). regions 8x4, NRX=1. split-K = nsplit.
  gemm_mfma<false, false><<<dim3(HID / 128, NTOK / 128, nsplit), 512, 0, stream>>>(
      interbf, wd_bf, nullptr, out, parts, NTOK, HID, INTERDIM / nsplit, INTERDIM, 8, 4, 1);

  // expert embeds -> fp8 (one launch; overlays interbf/hs_bf which are now dead)
  cast2_kernel<<<32768, 256, 0, stream>>>(dwe, upe, (unsigned*)dwe_f8, (unsigned*)upe_f8);
  if (nsplit == 4)
    expert_kernel<3><<<NTOK, 256, 0, stream>>>(hs, dwe_f8, upe_f8, idxb, probb, parts, out);
  else if (nsplit == 2)
    expert_kernel<1><<<NTOK, 256, 0, stream>>>(hs, dwe_f8, upe_f8, idxb, probb, parts, out);
  else
    expert_kernel<0><<<NTOK, 256, 0, stream>>>(hs, dwe_f8, upe_f8, idxb, probb, nullptr, out);
}